// Round 4
// baseline (495.632 us; speedup 1.0000x reference)
//
#include <hip/hip_runtime.h>
#include <math.h>

// Problem constants
#define CC   512
#define HH   64
#define WW   64
#define HWN  4096      // H*W
#define HEADS 8
#define GROUPS 4
#define HC   64        // C/HEADS
#define CG   128       // C/GROUPS
#define NS   1024      // Hk*Wk = 32*32
#define HK   32
#define SCALE 0.125f   // 64^-0.5
#define RPE_W 127      // 2*H-1
#define RPE_N 16129    // 127*127

// ---------------------------------------------------------------------------
// Generic tiled fp32 GEMM: C[o][n] = sum_c A[o][c]*B[c][n] + bias[o]
// BM=BN=64, BK=32, 256 threads, 4x4 per thread.
// ---------------------------------------------------------------------------
__global__ __launch_bounds__(256) void gemm_bias_kernel(
    const float* __restrict__ A, const float* __restrict__ B,
    const float* __restrict__ bias, float* __restrict__ C,
    int N, int K)
{
  __shared__ __align__(16) float As[32][64];
  __shared__ __align__(16) float Bs[32][64];
  const int bn0 = blockIdx.x * 64;
  const int bm0 = blockIdx.y * 64;
  const int tid = threadIdx.x;
  const int tx = tid & 15, ty = tid >> 4;
  float acc[4][4] = {};

  const int am = tid >> 2;            // 0..63
  const int ak = (tid & 3) * 8;       // 0,8,16,24
  const int bn = tid & 63;
  const int bk = (tid >> 6) * 8;      // 0,8,16,24

  for (int kt = 0; kt < K; kt += 32) {
    // A tile: 64m x 32k, two float4 per thread along k
    float4 a0 = *(const float4*)&A[(size_t)(bm0 + am) * K + kt + ak];
    float4 a1 = *(const float4*)&A[(size_t)(bm0 + am) * K + kt + ak + 4];
    As[ak + 0][am] = a0.x; As[ak + 1][am] = a0.y;
    As[ak + 2][am] = a0.z; As[ak + 3][am] = a0.w;
    As[ak + 4][am] = a1.x; As[ak + 5][am] = a1.y;
    As[ak + 6][am] = a1.z; As[ak + 7][am] = a1.w;
    // B tile: 32k x 64n, coalesced along n
    #pragma unroll
    for (int r = 0; r < 8; ++r)
      Bs[bk + r][bn] = B[(size_t)(kt + bk + r) * N + bn0 + bn];
    __syncthreads();
    #pragma unroll
    for (int kk = 0; kk < 32; ++kk) {
      float4 a = *(const float4*)&As[kk][ty * 4];
      float4 b = *(const float4*)&Bs[kk][tx * 4];
      acc[0][0] += a.x * b.x; acc[0][1] += a.x * b.y; acc[0][2] += a.x * b.z; acc[0][3] += a.x * b.w;
      acc[1][0] += a.y * b.x; acc[1][1] += a.y * b.y; acc[1][2] += a.y * b.z; acc[1][3] += a.y * b.w;
      acc[2][0] += a.z * b.x; acc[2][1] += a.z * b.y; acc[2][2] += a.z * b.z; acc[2][3] += a.z * b.w;
      acc[3][0] += a.w * b.x; acc[3][1] += a.w * b.y; acc[3][2] += a.w * b.z; acc[3][3] += a.w * b.w;
    }
    __syncthreads();
  }
  #pragma unroll
  for (int i = 0; i < 4; ++i) {
    float bi = bias[bm0 + ty * 4 + i];
    #pragma unroll
    for (int j = 0; j < 4; ++j)
      C[(size_t)(bm0 + ty * 4 + i) * N + bn0 + tx * 4 + j] = acc[i][j] + bi;
  }
}

// ---------------------------------------------------------------------------
// Depthwise 5x5 stride-2 conv, one block per (group, channel) plane.
// Stages the 64x64 input plane in LDS (coalesced float4), weights are
// wave-uniform scalar loads. Writes t position-major: t[g][p][c] so the
// LN kernel reads 128 consecutive floats per position.
// ---------------------------------------------------------------------------
__global__ __launch_bounds__(256) void dwconv_kernel(
    const float* __restrict__ q,       // [512][4096]
    const float* __restrict__ w_dw,    // [128][25]
    const float* __restrict__ b_dw,    // [128]
    float* __restrict__ t_ws)          // [4][1024][128]
{
  __shared__ __align__(16) float plane[HWN];
  const int c = blockIdx.x;            // 0..127 channel within group
  const int g = blockIdx.y;            // 0..3
  const int tid = threadIdx.x;

  // stage input plane: 4096 floats, coalesced float4
  const float* qplane = q + (size_t)(g * CG + c) * HWN;
  for (int i = tid; i < HWN / 4; i += 256)
    ((float4*)plane)[i] = ((const float4*)qplane)[i];

  // weights (block-uniform -> scalar regs)
  float wreg[25];
  #pragma unroll
  for (int t = 0; t < 25; ++t) wreg[t] = w_dw[c * 25 + t];
  const float bias = b_dw[c];

  __syncthreads();

  #pragma unroll
  for (int k = 0; k < 4; ++k) {
    int p = (k << 8) | tid;            // 0..1023
    int oy = p >> 5, ox = p & 31;
    int iy0 = oy * 2 - 2, ix0 = ox * 2 - 2;
    float acc = bias;
    #pragma unroll
    for (int ky = 0; ky < 5; ++ky) {
      int iy = iy0 + ky;
      bool yok = (iy >= 0) & (iy <= 63);
      int iyc = min(max(iy, 0), 63);
      #pragma unroll
      for (int kx = 0; kx < 5; ++kx) {
        int ix = ix0 + kx;
        bool ok = yok & (ix >= 0) & (ix <= 63);
        int ixc = min(max(ix, 0), 63);
        float v = plane[iyc * 64 + ixc];
        acc += wreg[ky * 5 + kx] * (ok ? v : 0.f);
      }
    }
    t_ws[(size_t)(((g << 10) | p) << 7) + c] = acc;
  }
}

// ---------------------------------------------------------------------------
// LayerNorm(ch) -> GELU(erf) -> 1x1 (128->2) -> tanh*range -> pos = off + ref.
// One block (128 threads) per (g,p); input read is 128 consecutive floats.
// ---------------------------------------------------------------------------
__device__ __forceinline__ float block_sum_128(float v, float* red, int c) {
  red[c] = v;
  __syncthreads();
  #pragma unroll
  for (int s = 64; s > 0; s >>= 1) {
    if (c < s) red[c] += red[c + s];
    __syncthreads();
  }
  float r = red[0];
  __syncthreads();
  return r;
}

__global__ __launch_bounds__(128) void lnpw_kernel(
    const float* __restrict__ t_ws,    // [4][1024][128]
    const float* __restrict__ ln_g, const float* __restrict__ ln_b,
    const float* __restrict__ w_pw,    // [2][128]
    float* __restrict__ pos_ws,        // [4][1024][2]
    float* __restrict__ pos_out,       // [4][32][32][2]
    float* __restrict__ ref_out)       // [4][32][32][2]
{
  __shared__ float red[128];
  const int blk = blockIdx.x;          // g*1024 + p
  const int g = blk >> 10, p = blk & 1023;
  const int oy = p >> 5, ox = p & 31;
  const int c = threadIdx.x;

  float t = t_ws[(size_t)blk * CG + c];
  float mu = block_sum_128(t, red, c) * (1.f / 128.f);
  float d = t - mu;
  float var = block_sum_128(d * d, red, c) * (1.f / 128.f);
  float u = d * rsqrtf(var + 1e-5f) * ln_g[c] + ln_b[c];
  float ge = 0.5f * u * (1.f + erff(u * 0.70710678118654752f));
  float sy = block_sum_128(w_pw[c] * ge, red, c);
  float sx = block_sum_128(w_pw[128 + c] * ge, red, c);
  if (c == 0) {
    const float scale = 2.0f / 32.0f;   // OFR(2.0) * (1/Hk)
    float offy = tanhf(sy) * scale;
    float offx = tanhf(sx) * scale;
    float refy = ((float)oy + 0.5f) * (2.f / 32.f) - 1.f;
    float refx = ((float)ox + 0.5f) * (2.f / 32.f) - 1.f;
    float py = offy + refy, px = offx + refx;
    int o = (g << 10) | p;
    pos_ws[o * 2 + 0] = py;  pos_ws[o * 2 + 1] = px;
    pos_out[o * 2 + 0] = py; pos_out[o * 2 + 1] = px;
    ref_out[o * 2 + 0] = refy; ref_out[o * 2 + 1] = refx;
  }
}

// ---------------------------------------------------------------------------
// Bilinear tap with per-tap zero padding (reference _gather semantics)
// ---------------------------------------------------------------------------
__device__ __forceinline__ float tap_img(const float* __restrict__ img,
                                         float xf, float yf, float lim, int Wr) {
  bool v = (xf >= 0.f) & (xf <= lim) & (yf >= 0.f) & (yf <= lim);
  float xc = fminf(fmaxf(xf, 0.f), lim);
  float yc = fminf(fmaxf(yf, 0.f), lim);
  int ix = (int)xc, iy = (int)yc;
  float val = img[iy * Wr + ix];
  return v ? val : 0.f;
}

// xs[c][p] = bilinear(x[c], pos[g(c)][p]) with align_corners=True, zeros pad
__global__ __launch_bounds__(256) void sample_kernel(
    const float* __restrict__ x, const float* __restrict__ pos_ws,
    float* __restrict__ xs)
{
  int t = blockIdx.x * 256 + threadIdx.x;   // 0 .. 512*1024-1
  int c = t >> 10;
  int p = t & 1023;
  int g = c >> 7;
  float py = pos_ws[((g << 10) | p) * 2 + 0];
  float px = pos_ws[((g << 10) | p) * 2 + 1];
  float gx = (px + 1.f) * 0.5f * 63.f;
  float gy = (py + 1.f) * 0.5f * 63.f;
  float x0 = floorf(gx), y0 = floorf(gy);
  float wx = gx - x0, wy = gy - y0;
  const float* img = x + (size_t)c * HWN;
  float v00 = tap_img(img, x0,       y0,       63.f, 64);
  float v01 = tap_img(img, x0 + 1.f, y0,       63.f, 64);
  float v10 = tap_img(img, x0,       y0 + 1.f, 63.f, 64);
  float v11 = tap_img(img, x0 + 1.f, y0 + 1.f, 63.f, 64);
  xs[(size_t)c * NS + p] =
      (v00 * (1.f - wx) + v01 * wx) * (1.f - wy) +
      (v10 * (1.f - wx) + v11 * wx) * wy;
}

// ---------------------------------------------------------------------------
// Fused flash-style attention with rpe-bias grid-sample.
// Block: (m-tile of 64 rows = one image row, head). 256 threads, 4x4 tile.
// n-fragment mapping permuted: thread (tx,ty) owns n = 16*j + tx  (j=0..3),
// so per tap-load the 16 tx-lanes hold CONSECUTIVE sample points ->
// contiguous rpe rows/x -> few cache lines per gather.
// Physical K layout: kv[ch][pn], pn = 4*(n&15) + (n>>4)  (so the float4
// b-fragment read kv[ch][tx*4] is unchanged). Softmax rows still reduce
// within the 16-lane shuffle group.
// ---------------------------------------------------------------------------
__global__ __launch_bounds__(256) void attn_kernel(
    const float* __restrict__ q,    // [512][4096]
    const float* __restrict__ kb,   // [512][1024]
    const float* __restrict__ vb,   // [512][1024]
    const float* __restrict__ pos,  // [4][1024][2]
    const float* __restrict__ rpe,  // [8][127][127]
    float* __restrict__ ob)         // [512][4096]
{
  __shared__ __align__(16) float qs[64][64];   // [ch][m]
  __shared__ __align__(16) float kv[64][68];   // K: [ch][pn]; then V: [n][ch]
  __shared__ __align__(16) float ps[64][72];   // P: [n][m]
  __shared__ float posn[64][2];

  const int h = blockIdx.y;
  const int m0 = blockIdx.x * 64;
  const int g = h >> 1;
  const int tid = threadIdx.x;
  const int tx = tid & 15, ty = tid >> 4;
  const float* rpeh = rpe + h * RPE_N;

  // stage Q tile [64ch][64m]
  for (int i = tid; i < 64 * 64; i += 256) {
    int ch = i >> 6, m = i & 63;
    qs[ch][m] = q[(size_t)(h * HC + ch) * HWN + m0 + m];
  }

  // per-block constants: my = m0>>6 is constant; mx = ty*4+i
  const float qgy = ((float)(m0 >> 6) + 0.5f) * (2.f / 64.f) - 1.f;
  const float ayp = qgy * 31.5f + 63.f;          // gy = ayp - py*31.5
  float axp[4];
  #pragma unroll
  for (int i = 0; i < 4; ++i) {
    float qgx = ((float)(ty * 4 + i) + 0.5f) * (2.f / 64.f) - 1.f;
    axp[i] = qgx * 31.5f + 63.f;                 // gx = axp[i] - px*31.5
  }

  float mrun[4], lrun[4], O[4][4];
  #pragma unroll
  for (int i = 0; i < 4; ++i) {
    mrun[i] = -INFINITY; lrun[i] = 0.f;
    #pragma unroll
    for (int j = 0; j < 4; ++j) O[i][j] = 0.f;
  }

  for (int n0 = 0; n0 < NS; n0 += 64) {
    __syncthreads();   // protect kv/ps reuse from previous chunk
    // stage K permuted: kv[ch][4*(n&15) + (n>>4)] = K[ch][n0+n]
    for (int i = tid; i < 64 * 64; i += 256) {
      int ch = i >> 6, n = i & 63;
      kv[ch][((n & 15) << 2) | (n >> 4)] = kb[(size_t)(h * HC + ch) * NS + n0 + n];
    }
    if (tid < 128)
      posn[tid >> 1][tid & 1] = pos[(size_t)((g << 10) + n0 + (tid >> 1)) * 2 + (tid & 1)];
    __syncthreads();

    // per-j y-precompute (n = 16*j + tx); gy depends on n only
    float wyv[4], bxv[4];
    int   r0[4], r1[4];
    bool  yv0[4], yv1[4];
    #pragma unroll
    for (int j = 0; j < 4; ++j) {
      float py = posn[16 * j + tx][0];
      float px = posn[16 * j + tx][1];
      bxv[j] = px * 31.5f;
      float gy = ayp - py * 31.5f;
      float y0f = floorf(gy);
      wyv[j] = gy - y0f;
      yv0[j] = (y0f >= 0.f) & (y0f <= 126.f);
      yv1[j] = (y0f >= -1.f) & (y0f <= 125.f);
      int y0c = (int)fminf(fmaxf(y0f, 0.f), 126.f);
      int y1c = (int)fminf(fmaxf(y0f + 1.f, 0.f), 126.f);
      r0[j] = y0c * RPE_W;
      r1[j] = y1c * RPE_W;
    }

    // S tile: s[i][j] = sum_ch q[m=ty*4+i][ch] * k[n=16j+tx][ch]
    float s[4][4] = {};
    #pragma unroll
    for (int ch = 0; ch < 64; ++ch) {
      float4 a = *(const float4*)&qs[ch][ty * 4];
      float4 b = *(const float4*)&kv[ch][tx * 4];
      s[0][0] += a.x * b.x; s[0][1] += a.x * b.y; s[0][2] += a.x * b.z; s[0][3] += a.x * b.w;
      s[1][0] += a.y * b.x; s[1][1] += a.y * b.y; s[1][2] += a.y * b.z; s[1][3] += a.y * b.w;
      s[2][0] += a.z * b.x; s[2][1] += a.z * b.y; s[2][2] += a.z * b.z; s[2][3] += a.z * b.w;
      s[3][0] += a.w * b.x; s[3][1] += a.w * b.y; s[3][2] += a.w * b.z; s[3][3] += a.w * b.w;
    }

    // scale + rpe bias (x-taps only; y hoisted)
    #pragma unroll
    for (int j = 0; j < 4; ++j) {
      float wy1 = wyv[j], wy0 = 1.f - wy1;
      #pragma unroll
      for (int i = 0; i < 4; ++i) {
        float gx = axp[i] - bxv[j];
        float x0f = floorf(gx);
        float wx = gx - x0f;
        bool xv0 = (x0f >= 0.f) & (x0f <= 126.f);
        bool xv1 = (x0f >= -1.f) & (x0f <= 125.f);
        int xi0 = (int)fminf(fmaxf(x0f, 0.f), 126.f);
        int xi1 = (int)fminf(fmaxf(x0f + 1.f, 0.f), 126.f);
        float t00 = rpeh[r0[j] + xi0];
        float t01 = rpeh[r0[j] + xi1];
        float t10 = rpeh[r1[j] + xi0];
        float t11 = rpeh[r1[j] + xi1];
        float v00 = (xv0 & yv0[j]) ? t00 : 0.f;
        float v01 = (xv1 & yv0[j]) ? t01 : 0.f;
        float v10 = (xv0 & yv1[j]) ? t10 : 0.f;
        float v11 = (xv1 & yv1[j]) ? t11 : 0.f;
        float bt = v00 * (1.f - wx) + v01 * wx;
        float bb = v10 * (1.f - wx) + v11 * wx;
        s[i][j] = s[i][j] * SCALE + bt * wy0 + bb * wy1;
      }
    }

    // online softmax (row m = ty*4+i spans the 16 tx-lanes)
    float pl[4][4];
    #pragma unroll
    for (int i = 0; i < 4; ++i) {
      float rm = fmaxf(fmaxf(s[i][0], s[i][1]), fmaxf(s[i][2], s[i][3]));
      rm = fmaxf(rm, __shfl_xor(rm, 1, 16));
      rm = fmaxf(rm, __shfl_xor(rm, 2, 16));
      rm = fmaxf(rm, __shfl_xor(rm, 4, 16));
      rm = fmaxf(rm, __shfl_xor(rm, 8, 16));
      float mnew = fmaxf(mrun[i], rm);
      float alpha = __expf(mrun[i] - mnew);
      mrun[i] = mnew;
      float rs = 0.f;
      #pragma unroll
      for (int j = 0; j < 4; ++j) {
        pl[i][j] = __expf(s[i][j] - mnew);
        rs += pl[i][j];
      }
      rs += __shfl_xor(rs, 1, 16);
      rs += __shfl_xor(rs, 2, 16);
      rs += __shfl_xor(rs, 4, 16);
      rs += __shfl_xor(rs, 8, 16);
      lrun[i] = lrun[i] * alpha + rs;
      #pragma unroll
      for (int j = 0; j < 4; ++j) O[i][j] *= alpha;
    }

    __syncthreads();   // all waves done reading kv as K
    // write P (float4 over i): ps[n = 16j+tx][m = ty*4 .. +3]
    #pragma unroll
    for (int j = 0; j < 4; ++j) {
      float4 pw;
      pw.x = pl[0][j]; pw.y = pl[1][j]; pw.z = pl[2][j]; pw.w = pl[3][j];
      *(float4*)&ps[16 * j + tx][ty * 4] = pw;
    }
    // stage V as kv[n][ch]; lane map keeps LDS writes conflict-free
    for (int i = tid; i < 64 * 64; i += 256) {
      int ch = (i & 3) | ((i >> 8) << 2);
      int n = (i >> 2) & 63;
      kv[n][ch] = vb[(size_t)(h * HC + ch) * NS + n0 + n];
    }
    __syncthreads();

    // O += P V : O[i][j] over (m = ty*4+i, ch = tx*4+j)
    #pragma unroll
    for (int n = 0; n < 64; ++n) {
      float4 p4 = *(const float4*)&ps[n][ty * 4];
      float4 v4 = *(const float4*)&kv[n][tx * 4];
      O[0][0] += p4.x * v4.x; O[0][1] += p4.x * v4.y; O[0][2] += p4.x * v4.z; O[0][3] += p4.x * v4.w;
      O[1][0] += p4.y * v4.x; O[1][1] += p4.y * v4.y; O[1][2] += p4.y * v4.z; O[1][3] += p4.y * v4.w;
      O[2][0] += p4.z * v4.x; O[2][1] += p4.z * v4.y; O[2][2] += p4.z * v4.z; O[2][3] += p4.z * v4.w;
      O[3][0] += p4.w * v4.x; O[3][1] += p4.w * v4.y; O[3][2] += p4.w * v4.z; O[3][3] += p4.w * v4.w;
    }
  }

  // normalize + transpose through LDS for coalesced store
  __syncthreads();
  #pragma unroll
  for (int i = 0; i < 4; ++i) {
    float inv = 1.f / lrun[i];
    #pragma unroll
    for (int j = 0; j < 4; ++j)
      kv[tx * 4 + j][ty * 4 + i] = O[i][j] * inv;
  }
  __syncthreads();
  for (int i = tid; i < 64 * 64; i += 256) {
    int ch = i >> 6, m = i & 63;
    ob[(size_t)(h * HC + ch) * HWN + m0 + m] = kv[ch][m];
  }
}

// ---------------------------------------------------------------------------
extern "C" void kernel_launch(void* const* d_in, const int* in_sizes, int n_in,
                              void* d_out, int out_size, void* d_ws, size_t ws_size,
                              hipStream_t stream) {
  const float* x     = (const float*)d_in[0];
  const float* wq    = (const float*)d_in[1];
  const float* bq    = (const float*)d_in[2];
  const float* wk    = (const float*)d_in[3];
  const float* bk    = (const float*)d_in[4];
  const float* wv    = (const float*)d_in[5];
  const float* bv    = (const float*)d_in[6];
  const float* wo    = (const float*)d_in[7];
  const float* bo    = (const float*)d_in[8];
  const float* w_dw  = (const float*)d_in[9];
  const float* b_dw  = (const float*)d_in[10];
  const float* ln_g  = (const float*)d_in[11];
  const float* ln_b  = (const float*)d_in[12];
  const float* w_pw  = (const float*)d_in[13];
  const float* rpe   = (const float*)d_in[14];

  float* out = (float*)d_out;
  float* y_out   = out;                         // [512][4096]
  float* pos_out = out + 2097152;               // [4][32][32][2]
  float* ref_out = out + 2097152 + 8192;        // [4][32][32][2]

  float* ws = (float*)d_ws;
  float* qbuf  = ws;                  // 2097152
  float* posws = qbuf + 2097152;      // 8192
  float* xsbuf = posws + 8192;        // 524288 (aliases t_ws: consumed before sample)
  float* kbuf  = xsbuf + 524288;      // 524288
  float* vbuf  = kbuf + 524288;       // 524288
  float* obuf  = vbuf + 524288;       // 2097152
  float* t_ws  = xsbuf;               // [4][1024][128] = 524288, exact fit

  // q = wq @ x + bq
  gemm_bias_kernel<<<dim3(HWN / 64, CC / 64), 256, 0, stream>>>(wq, x, bq, qbuf, HWN, CC);
  // conv_offset stage 1: depthwise conv (coalesced, LDS-staged planes)
  dwconv_kernel<<<dim3(CG, GROUPS), 256, 0, stream>>>(qbuf, w_dw, b_dw, t_ws);
  // conv_offset stage 2: LN -> GELU -> pw -> tanh -> pos (+ pos/ref outputs)
  lnpw_kernel<<<dim3(GROUPS * NS), 128, 0, stream>>>(t_ws, ln_g, ln_b, w_pw,
                                                     posws, pos_out, ref_out);
  // xs = grid_sample(x, pos)
  sample_kernel<<<dim3(CC * NS / 256), 256, 0, stream>>>(x, posws, xsbuf);
  // k, v
  gemm_bias_kernel<<<dim3(NS / 64, CC / 64), 256, 0, stream>>>(wk, xsbuf, bk, kbuf, NS, CC);
  gemm_bias_kernel<<<dim3(NS / 64, CC / 64), 256, 0, stream>>>(wv, xsbuf, bv, vbuf, NS, CC);
  // fused attention
  attn_kernel<<<dim3(HWN / 64, HEADS), 256, 0, stream>>>(qbuf, kbuf, vbuf, posws, rpe, obuf);
  // y = wo @ out + bo
  gemm_bias_kernel<<<dim3(HWN / 64, CC / 64), 256, 0, stream>>>(wo, obuf, bo, y_out, HWN, CC);
}

// Round 6
// 415.053 us; speedup vs baseline: 1.1941x; 1.1941x over previous
//
#include <hip/hip_runtime.h>
#include <hip/hip_fp16.h>
#include <math.h>

// Problem constants
#define CC   512
#define HH   64
#define WW   64
#define HWN  4096      // H*W
#define HEADS 8
#define GROUPS 4
#define HC   64        // C/HEADS
#define CG   128       // C/GROUPS
#define NS   1024      // Hk*Wk = 32*32
#define HK   32
#define SCALE 0.125f   // 64^-0.5
#define RPE_W 127      // 2*H-1
#define RPE_N 16129    // 127*127

typedef _Float16 f16x8 __attribute__((ext_vector_type(8)));
typedef float f32x4 __attribute__((ext_vector_type(4)));

// ---------------------------------------------------------------------------
// Generic tiled fp32 GEMM: C[o][n] = sum_c A[o][c]*B[c][n] + bias[o]
// BM=BN=64, BK=32, 256 threads, 4x4 per thread.  (unchanged, verified R4)
// ---------------------------------------------------------------------------
__global__ __launch_bounds__(256) void gemm_bias_kernel(
    const float* __restrict__ A, const float* __restrict__ B,
    const float* __restrict__ bias, float* __restrict__ C,
    int N, int K)
{
  __shared__ __align__(16) float As[32][64];
  __shared__ __align__(16) float Bs[32][64];
  const int bn0 = blockIdx.x * 64;
  const int bm0 = blockIdx.y * 64;
  const int tid = threadIdx.x;
  const int tx = tid & 15, ty = tid >> 4;
  float acc[4][4] = {};

  const int am = tid >> 2;
  const int ak = (tid & 3) * 8;
  const int bn = tid & 63;
  const int bk = (tid >> 6) * 8;

  for (int kt = 0; kt < K; kt += 32) {
    float4 a0 = *(const float4*)&A[(size_t)(bm0 + am) * K + kt + ak];
    float4 a1 = *(const float4*)&A[(size_t)(bm0 + am) * K + kt + ak + 4];
    As[ak + 0][am] = a0.x; As[ak + 1][am] = a0.y;
    As[ak + 2][am] = a0.z; As[ak + 3][am] = a0.w;
    As[ak + 4][am] = a1.x; As[ak + 5][am] = a1.y;
    As[ak + 6][am] = a1.z; As[ak + 7][am] = a1.w;
    #pragma unroll
    for (int r = 0; r < 8; ++r)
      Bs[bk + r][bn] = B[(size_t)(kt + bk + r) * N + bn0 + bn];
    __syncthreads();
    #pragma unroll
    for (int kk = 0; kk < 32; ++kk) {
      float4 a = *(const float4*)&As[kk][ty * 4];
      float4 b = *(const float4*)&Bs[kk][tx * 4];
      acc[0][0] += a.x * b.x; acc[0][1] += a.x * b.y; acc[0][2] += a.x * b.z; acc[0][3] += a.x * b.w;
      acc[1][0] += a.y * b.x; acc[1][1] += a.y * b.y; acc[1][2] += a.y * b.z; acc[1][3] += a.y * b.w;
      acc[2][0] += a.z * b.x; acc[2][1] += a.z * b.y; acc[2][2] += a.z * b.z; acc[2][3] += a.z * b.w;
      acc[3][0] += a.w * b.x; acc[3][1] += a.w * b.y; acc[3][2] += a.w * b.z; acc[3][3] += a.w * b.w;
    }
    __syncthreads();
  }
  #pragma unroll
  for (int i = 0; i < 4; ++i) {
    float bi = bias[bm0 + ty * 4 + i];
    #pragma unroll
    for (int j = 0; j < 4; ++j)
      C[(size_t)(bm0 + ty * 4 + i) * N + bn0 + tx * 4 + j] = acc[i][j] + bi;
  }
}

// ---------------------------------------------------------------------------
// Depthwise 5x5 stride-2 conv (unchanged, verified R4)
// ---------------------------------------------------------------------------
__global__ __launch_bounds__(256) void dwconv_kernel(
    const float* __restrict__ q, const float* __restrict__ w_dw,
    const float* __restrict__ b_dw, float* __restrict__ t_ws)
{
  __shared__ __align__(16) float plane[HWN];
  const int c = blockIdx.x;
  const int g = blockIdx.y;
  const int tid = threadIdx.x;

  const float* qplane = q + (size_t)(g * CG + c) * HWN;
  for (int i = tid; i < HWN / 4; i += 256)
    ((float4*)plane)[i] = ((const float4*)qplane)[i];

  float wreg[25];
  #pragma unroll
  for (int t = 0; t < 25; ++t) wreg[t] = w_dw[c * 25 + t];
  const float bias = b_dw[c];

  __syncthreads();

  #pragma unroll
  for (int k = 0; k < 4; ++k) {
    int p = (k << 8) | tid;
    int oy = p >> 5, ox = p & 31;
    int iy0 = oy * 2 - 2, ix0 = ox * 2 - 2;
    float acc = bias;
    #pragma unroll
    for (int ky = 0; ky < 5; ++ky) {
      int iy = iy0 + ky;
      bool yok = (iy >= 0) & (iy <= 63);
      int iyc = min(max(iy, 0), 63);
      #pragma unroll
      for (int kx = 0; kx < 5; ++kx) {
        int ix = ix0 + kx;
        bool ok = yok & (ix >= 0) & (ix <= 63);
        int ixc = min(max(ix, 0), 63);
        float v = plane[iyc * 64 + ixc];
        acc += wreg[ky * 5 + kx] * (ok ? v : 0.f);
      }
    }
    t_ws[(size_t)(((g << 10) | p) << 7) + c] = acc;
  }
}

// ---------------------------------------------------------------------------
// LN -> GELU -> 1x1 -> tanh -> pos  (unchanged, verified R4)
// ---------------------------------------------------------------------------
__device__ __forceinline__ float block_sum_128(float v, float* red, int c) {
  red[c] = v;
  __syncthreads();
  #pragma unroll
  for (int s = 64; s > 0; s >>= 1) {
    if (c < s) red[c] += red[c + s];
    __syncthreads();
  }
  float r = red[0];
  __syncthreads();
  return r;
}

__global__ __launch_bounds__(128) void lnpw_kernel(
    const float* __restrict__ t_ws,
    const float* __restrict__ ln_g, const float* __restrict__ ln_b,
    const float* __restrict__ w_pw,
    float* __restrict__ pos_ws, float* __restrict__ pos_out,
    float* __restrict__ ref_out)
{
  __shared__ float red[128];
  const int blk = blockIdx.x;
  const int g = blk >> 10, p = blk & 1023;
  const int oy = p >> 5, ox = p & 31;
  const int c = threadIdx.x;

  float t = t_ws[(size_t)blk * CG + c];
  float mu = block_sum_128(t, red, c) * (1.f / 128.f);
  float d = t - mu;
  float var = block_sum_128(d * d, red, c) * (1.f / 128.f);
  float u = d * rsqrtf(var + 1e-5f) * ln_g[c] + ln_b[c];
  float ge = 0.5f * u * (1.f + erff(u * 0.70710678118654752f));
  float sy = block_sum_128(w_pw[c] * ge, red, c);
  float sx = block_sum_128(w_pw[128 + c] * ge, red, c);
  if (c == 0) {
    const float scale = 2.0f / 32.0f;
    float offy = tanhf(sy) * scale;
    float offx = tanhf(sx) * scale;
    float refy = ((float)oy + 0.5f) * (2.f / 32.f) - 1.f;
    float refx = ((float)ox + 0.5f) * (2.f / 32.f) - 1.f;
    float py = offy + refy, px = offx + refx;
    int o = (g << 10) | p;
    pos_ws[o * 2 + 0] = py;  pos_ws[o * 2 + 1] = px;
    pos_out[o * 2 + 0] = py; pos_out[o * 2 + 1] = px;
    ref_out[o * 2 + 0] = refy; ref_out[o * 2 + 1] = refx;
  }
}

// ---------------------------------------------------------------------------
// Bilinear tap (unchanged, verified R4)
// ---------------------------------------------------------------------------
__device__ __forceinline__ float tap_img(const float* __restrict__ img,
                                         float xf, float yf, float lim, int Wr) {
  bool v = (xf >= 0.f) & (xf <= lim) & (yf >= 0.f) & (yf <= lim);
  float xc = fminf(fmaxf(xf, 0.f), lim);
  float yc = fminf(fmaxf(yf, 0.f), lim);
  int ix = (int)xc, iy = (int)yc;
  float val = img[iy * Wr + ix];
  return v ? val : 0.f;
}

__global__ __launch_bounds__(256) void sample_kernel(
    const float* __restrict__ x, const float* __restrict__ pos_ws,
    float* __restrict__ xs)
{
  int t = blockIdx.x * 256 + threadIdx.x;
  int c = t >> 10;
  int p = t & 1023;
  int g = c >> 7;
  float py = pos_ws[((g << 10) | p) * 2 + 0];
  float px = pos_ws[((g << 10) | p) * 2 + 1];
  float gx = (px + 1.f) * 0.5f * 63.f;
  float gy = (py + 1.f) * 0.5f * 63.f;
  float x0 = floorf(gx), y0 = floorf(gy);
  float wx = gx - x0, wy = gy - y0;
  const float* img = x + (size_t)c * HWN;
  float v00 = tap_img(img, x0,       y0,       63.f, 64);
  float v01 = tap_img(img, x0 + 1.f, y0,       63.f, 64);
  float v10 = tap_img(img, x0,       y0 + 1.f, 63.f, 64);
  float v11 = tap_img(img, x0 + 1.f, y0 + 1.f, 63.f, 64);
  xs[(size_t)c * NS + p] =
      (v00 * (1.f - wx) + v01 * wx) * (1.f - wy) +
      (v10 * (1.f - wx) + v11 * wx) * wy;
}

// ---------------------------------------------------------------------------
// Split helpers: x = hi(fp16) + lo(fp16), |err| ~ 2^-22 |x|
// ---------------------------------------------------------------------------
__device__ __forceinline__ void split_f16(float x, ushort& h, ushort& l) {
  __half xh = __float2half(x);
  float hf = __half2float(xh);
  __half xl = __float2half(x - hf);
  h = __half_as_ushort(xh);
  l = __half_as_ushort(xl);
}

// Transpose + split: src [head*64+ch][ncols] fp32 -> dst [head][col][64ch] fp16
__global__ __launch_bounds__(256) void tsplit_kernel(
    const float* __restrict__ src, ushort* __restrict__ dh,
    ushort* __restrict__ dl, int ncols)
{
  __shared__ float tile[64][65];
  const int ct = blockIdx.x, hh = blockIdx.y;
  const int tid = threadIdx.x;
  for (int i = tid; i < 4096; i += 256) {
    int ch = i >> 6, m = i & 63;
    tile[ch][m] = src[(size_t)(hh * 64 + ch) * ncols + ct * 64 + m];
  }
  __syncthreads();
  for (int i = tid; i < 4096; i += 256) {
    int m = i >> 6, ch = i & 63;
    ushort h, l;
    split_f16(tile[ch][m], h, l);
    size_t o = ((size_t)hh * ncols + ct * 64 + m) * 64 + ch;
    dh[o] = h; dl[o] = l;
  }
}

// Elementwise split (layout preserved): V [512][1024]
__global__ __launch_bounds__(256) void vsplit_kernel(
    const float* __restrict__ src, ushort* __restrict__ dh,
    ushort* __restrict__ dl)
{
  int i = blockIdx.x * 256 + threadIdx.x;
  ushort h, l;
  split_f16(src[i], h, l);
  dh[i] = h; dl[i] = l;
}

// ---------------------------------------------------------------------------
// MFMA flash attention with rpe-bias grid-sample, split-fp16 (3-term) matmuls.
// Block (m0=bx*64 rows, head=by), 4 independent waves; wave w owns rows
// m0+w*16..+15.  Q loaded from fp32 qbuf and split in-kernel (once per block).
// K/V fragments straight from global (L2-hot); P round-trips through per-wave
// LDS (uint = hi|lo<<16, XOR-swizzled).  No block barriers anywhere.
// C-layout: col = lane&15, row = (lane>>4)*4 + reg  [verified m89/m91].
// A-layout: m = lane&15, k = (lane>>4)*8 + j.  B: k = (lane>>4)*8+j, n=lane&15.
// ---------------------------------------------------------------------------
__global__ __launch_bounds__(256) void attn_kernel(
    const float*  __restrict__ qb,  // [512][4096] fp32
    const ushort* __restrict__ kth, const ushort* __restrict__ ktl, // [8][1024][64]
    const ushort* __restrict__ vhb, const ushort* __restrict__ vlb, // [512][1024]
    const float* __restrict__ pos,  // [4][1024][2]
    const float* __restrict__ rpe,  // [8][127][127]
    float* __restrict__ ob)         // [512][4096]
{
  __shared__ __align__(16) uint ps32[4][16][64];   // P packed hi|lo, swizzled
  __shared__ float olds[4][64][17];                // output transpose staging

  const int h = blockIdx.y, m0 = blockIdx.x * 64, g = h >> 1;
  const int tid = threadIdx.x;
  const int w = tid >> 6, lane = tid & 63, l15 = lane & 15, lq = lane >> 4;
  const float* rpeh = rpe + h * RPE_N;

  // ---- persistent Q fragments (A operand): m = mg, k(ch) = kst*32 + lq*8 + j
  const int mg = m0 + w * 16 + l15;
  f16x8 qfh[2], qfl[2];
  #pragma unroll
  for (int kst = 0; kst < 2; ++kst) {
    union { f16x8 v; ushort u[8]; } Hh, Ll;
    #pragma unroll
    for (int j = 0; j < 8; ++j) {
      int ch = kst * 32 + lq * 8 + j;
      float qv = qb[((size_t)(h * 64 + ch)) * 4096 + mg];
      ushort hh, ll;
      split_f16(qv, hh, ll);
      Hh.u[j] = hh; Ll.u[j] = ll;
    }
    qfh[kst] = Hh.v; qfl[kst] = Ll.v;
  }

  // ---- bias constants (C-layout rows: m_local = w*16 + lq*4 + r)
  const float qgy = ((float)(m0 >> 6) + 0.5f) * (2.f / 64.f) - 1.f;
  const float ayp = qgy * 31.5f + 63.f;          // gy = ayp - py*31.5
  float axp[4];
  #pragma unroll
  for (int r = 0; r < 4; ++r) {
    int ml = w * 16 + lq * 4 + r;
    float qgx = ((float)ml + 0.5f) * (2.f / 64.f) - 1.f;
    axp[r] = qgx * 31.5f + 63.f;                 // gx = axp[r] - px*31.5
  }

  float mrun[4], lrun[4];
  f32x4 O[4];
  #pragma unroll
  for (int r = 0; r < 4; ++r) { mrun[r] = -INFINITY; lrun[r] = 0.f; }
  #pragma unroll
  for (int t = 0; t < 4; ++t) O[t] = (f32x4)0.f;

  for (int c = 0; c < 16; ++c) {
    const int n0c = c * 64;

    // ---- K fragments (B operand): k = kst*32+lq*8+j, n = n0c + nt*16 + l15
    f16x8 kfh[4][2], kfl[4][2];
    #pragma unroll
    for (int nt = 0; nt < 4; ++nt) {
      const ushort* b0 = kth + ((size_t)h * 1024 + n0c + nt * 16 + l15) * 64 + lq * 8;
      const ushort* b1 = ktl + ((size_t)h * 1024 + n0c + nt * 16 + l15) * 64 + lq * 8;
      kfh[nt][0] = *(const f16x8*)(b0);  kfh[nt][1] = *(const f16x8*)(b0 + 32);
      kfl[nt][0] = *(const f16x8*)(b1);  kfl[nt][1] = *(const f16x8*)(b1 + 32);
    }

    // ---- S = Q K^T (3-term split)
    f32x4 s[4];
    #pragma unroll
    for (int nt = 0; nt < 4; ++nt) {
      f32x4 acc = (f32x4)0.f;
      acc = __builtin_amdgcn_mfma_f32_16x16x32_f16(qfh[0], kfh[nt][0], acc, 0, 0, 0);
      acc = __builtin_amdgcn_mfma_f32_16x16x32_f16(qfh[0], kfl[nt][0], acc, 0, 0, 0);
      acc = __builtin_amdgcn_mfma_f32_16x16x32_f16(qfl[0], kfh[nt][0], acc, 0, 0, 0);
      acc = __builtin_amdgcn_mfma_f32_16x16x32_f16(qfh[1], kfh[nt][1], acc, 0, 0, 0);
      acc = __builtin_amdgcn_mfma_f32_16x16x32_f16(qfh[1], kfl[nt][1], acc, 0, 0, 0);
      acc = __builtin_amdgcn_mfma_f32_16x16x32_f16(qfl[1], kfh[nt][1], acc, 0, 0, 0);
      s[nt] = acc;
    }

    // ---- V fragments (B operand of PV): k-dim n = n0c+nst*32+lq*8+j, col = ch
    f16x8 vfh[4][2], vfl[4][2];
    #pragma unroll
    for (int ct = 0; ct < 4; ++ct) {
      const ushort* b0 = vhb + ((size_t)(h * 64 + ct * 16 + l15)) * 1024 + n0c + lq * 8;
      const ushort* b1 = vlb + ((size_t)(h * 64 + ct * 16 + l15)) * 1024 + n0c + lq * 8;
      vfh[ct][0] = *(const f16x8*)(b0);  vfh[ct][1] = *(const f16x8*)(b0 + 32);
      vfl[ct][0] = *(const f16x8*)(b1);  vfl[ct][1] = *(const f16x8*)(b1 + 32);
    }

    // ---- scale + rpe bias (per nt: n = n0c + nt*16 + l15)
    #pragma unroll
    for (int nt = 0; nt < 4; ++nt) {
      int n = n0c + nt * 16 + l15;
      float py = pos[((g << 10) | n) * 2 + 0];
      float px = pos[((g << 10) | n) * 2 + 1];
      float bx = px * 31.5f;
      float gy = ayp - py * 31.5f;
      float y0f = floorf(gy);
      float wy1 = gy - y0f, wy0 = 1.f - wy1;
      bool yv0 = (y0f >= 0.f) & (y0f <= 126.f);
      bool yv1 = (y0f >= -1.f) & (y0f <= 125.f);
      int rr0 = (int)fminf(fmaxf(y0f, 0.f), 126.f) * RPE_W;
      int rr1 = (int)fminf(fmaxf(y0f + 1.f, 0.f), 126.f) * RPE_W;
      #pragma unroll
      for (int r = 0; r < 4; ++r) {
        float gx = axp[r] - bx;
        float x0f = floorf(gx);
        float wx = gx - x0f;
        bool xv0 = (x0f >= 0.f) & (x0f <= 126.f);
        bool xv1 = (x0f >= -1.f) & (x0f <= 125.f);
        int xi0 = (int)fminf(fmaxf(x0f, 0.f), 126.f);
        int xi1 = (int)fminf(fmaxf(x0f + 1.f, 0.f), 126.f);
        float t00 = rpeh[rr0 + xi0];
        float t01 = rpeh[rr0 + xi1];
        float t10 = rpeh[rr1 + xi0];
        float t11 = rpeh[rr1 + xi1];
        float v00 = (xv0 & yv0) ? t00 : 0.f;
        float v01 = (xv1 & yv0) ? t01 : 0.f;
        float v10 = (xv0 & yv1) ? t10 : 0.f;
        float v11 = (xv1 & yv1) ? t11 : 0.f;
        float bt = v00 * (1.f - wx) + v01 * wx;
        float bb = v10 * (1.f - wx) + v11 * wx;
        s[nt][r] = s[nt][r] * SCALE + bt * wy0 + bb * wy1;
      }
    }

    // ---- online softmax (row = lq*4+r; cols span the 16 l15-lanes x 4 nt)
    #pragma unroll
    for (int r = 0; r < 4; ++r) {
      float rm = fmaxf(fmaxf(s[0][r], s[1][r]), fmaxf(s[2][r], s[3][r]));
      rm = fmaxf(rm, __shfl_xor(rm, 1, 16));
      rm = fmaxf(rm, __shfl_xor(rm, 2, 16));
      rm = fmaxf(rm, __shfl_xor(rm, 4, 16));
      rm = fmaxf(rm, __shfl_xor(rm, 8, 16));
      float mnew = fmaxf(mrun[r], rm);
      float alpha = __expf(mrun[r] - mnew);
      mrun[r] = mnew;
      float rs = 0.f;
      #pragma unroll
      for (int nt = 0; nt < 4; ++nt) {
        float p = __expf(s[nt][r] - mnew);
        s[nt][r] = p;
        rs += p;
      }
      rs += __shfl_xor(rs, 1, 16);
      rs += __shfl_xor(rs, 2, 16);
      rs += __shfl_xor(rs, 4, 16);
      rs += __shfl_xor(rs, 8, 16);
      lrun[r] = lrun[r] * alpha + rs;
      #pragma unroll
      for (int ct = 0; ct < 4; ++ct) O[ct][r] *= alpha;
    }

    // ---- P: split to fp16 hi/lo, pack to uint, write swizzled per-wave LDS
    #pragma unroll
    for (int nt = 0; nt < 4; ++nt) {
      #pragma unroll
      for (int r = 0; r < 4; ++r) {
        ushort hh, ll;
        split_f16(s[nt][r], hh, ll);
        uint packed = (uint)hh | ((uint)ll << 16);
        int m = lq * 4 + r;
        int n = nt * 16 + l15;
        ps32[w][m][(n & 3) | ((((n >> 2) ^ m) & 15) << 2)] = packed;
      }
    }

    // ---- P fragments (A operand): m = l15, k-dim n = nst*32 + lq*8 + j
    f16x8 pfh[2], pfl[2];
    #pragma unroll
    for (int nst = 0; nst < 2; ++nst) {
      int s0 = nst * 8 + lq * 2;
      uint4 u0 = *(const uint4*)&ps32[w][l15][((s0 ^ l15) & 15) << 2];
      uint4 u1 = *(const uint4*)&ps32[w][l15][(((s0 + 1) ^ l15) & 15) << 2];
      union { f16x8 v; ushort u[8]; } ah, al;
      uint t0[8] = {u0.x, u0.y, u0.z, u0.w, u1.x, u1.y, u1.z, u1.w};
      #pragma unroll
      for (int j = 0; j < 8; ++j) {
        ah.u[j] = (ushort)(t0[j] & 0xffffu);
        al.u[j] = (ushort)(t0[j] >> 16);
      }
      pfh[nst] = ah.v;
      pfl[nst] = al.v;
    }

    // ---- O += P V (3-term split)
    #pragma unroll
    for (int ct = 0; ct < 4; ++ct) {
      f32x4 acc = O[ct];
      acc = __builtin_amdgcn_mfma_f32_16x16x32_f16(pfh[0], vfh[ct][0], acc, 0, 0, 0);
      acc = __builtin_amdgcn_mfma_f32_16x16x32_f16(pfh[0], vfl[ct][0], acc, 0, 0, 0);
      acc = __builtin_amdgcn_mfma_f32_16x16x32_f16(pfl[0], vfh[ct][0], acc, 0, 0, 0);
      acc = __builtin_amdgcn_mfma_f32_16x16x32_f16(pfh[1], vfh[ct][1], acc, 0, 0, 0);
      acc = __builtin_amdgcn_mfma_f32_16x16x32_f16(pfh[1], vfl[ct][1], acc, 0, 0, 0);
      acc = __builtin_amdgcn_mfma_f32_16x16x32_f16(pfl[1], vfh[ct][1], acc, 0, 0, 0);
      O[ct] = acc;
    }
  }

  // ---- normalize + transpose via LDS for coalesced store (wave-internal)
  float inv[4];
  #pragma unroll
  for (int r = 0; r < 4; ++r) inv[r] = 1.f / lrun[r];
  #pragma unroll
  for (int ct = 0; ct < 4; ++ct)
    #pragma unroll
    for (int r = 0; r < 4; ++r)
      olds[w][ct * 16 + l15][lq * 4 + r] = O[ct][r] * inv[r];

  #pragma unroll
  for (int it = 0; it < 16; ++it) {
    int ch = it * 4 + lq;
    ob[((size_t)(h * 64 + ch)) * 4096 + m0 + w * 16 + l15] = olds[w][ch][l15];
  }
}

// ---------------------------------------------------------------------------
extern "C" void kernel_launch(void* const* d_in, const int* in_sizes, int n_in,
                              void* d_out, int out_size, void* d_ws, size_t ws_size,
                              hipStream_t stream) {
  const float* x     = (const float*)d_in[0];
  const float* wq    = (const float*)d_in[1];
  const float* bq    = (const float*)d_in[2];
  const float* wk    = (const float*)d_in[3];
  const float* bk    = (const float*)d_in[4];
  const float* wv    = (const float*)d_in[5];
  const float* bv    = (const float*)d_in[6];
  const float* wo    = (const float*)d_in[7];
  const float* bo    = (const float*)d_in[8];
  const float* w_dw  = (const float*)d_in[9];
  const float* b_dw  = (const float*)d_in[10];
  const float* ln_g  = (const float*)d_in[11];
  const float* ln_b  = (const float*)d_in[12];
  const float* w_pw  = (const float*)d_in[13];
  const float* rpe   = (const float*)d_in[14];

  float* out = (float*)d_out;
  float* y_out   = out;
  float* pos_out = out + 2097152;
  float* ref_out = out + 2097152 + 8192;

  // Workspace layout: identical 23.1 MB footprint to the verified round-4 run.
  float* ws = (float*)d_ws;
  float* qbuf  = ws;                   // 2097152 f
  float* posws = qbuf + 2097152;       // 8192 f
  float* xsbuf = posws + 8192;         // 524288 f (aliases t_ws, then kth/ktl)
  float* kbuf  = xsbuf + 524288;       // 524288 f (aliases vhb/vlb)
  float* vbuf  = kbuf + 524288;        // 524288 f
  float* obuf  = vbuf + 524288;        // 2097152 f
  float* t_ws  = xsbuf;
  // kth/ktl alias xsbuf (last read: k/v GEMMs). vhb/vlb alias kbuf (last
  // read: tsplit_k). Stream order guarantees producer/consumer safety.
  ushort* kth = (ushort*)xsbuf;        // [8][1024][64] = 524288 us = 1 MB
  ushort* ktl = kth + 524288;          // 1 MB  (kth+ktl = xsbuf's 2 MB)
  ushort* vhb = (ushort*)kbuf;         // [512][1024] = 1 MB
  ushort* vlb = vhb + 524288;          // 1 MB  (vhb+vlb = kbuf's 2 MB)

  // q = wq @ x + bq
  gemm_bias_kernel<<<dim3(HWN / 64, CC / 64), 256, 0, stream>>>(wq, x, bq, qbuf, HWN, CC);
  // conv_offset
  dwconv_kernel<<<dim3(CG, GROUPS), 256, 0, stream>>>(qbuf, w_dw, b_dw, t_ws);
  lnpw_kernel<<<dim3(GROUPS * NS), 128, 0, stream>>>(t_ws, ln_g, ln_b, w_pw,
                                                     posws, pos_out, ref_out);
  // xs = grid_sample(x, pos)
  sample_kernel<<<dim3(CC * NS / 256), 256, 0, stream>>>(x, posws, xsbuf);
  // k, v projections
  gemm_bias_kernel<<<dim3(NS / 64, CC / 64), 256, 0, stream>>>(wk, xsbuf, bk, kbuf, NS, CC);
  gemm_bias_kernel<<<dim3(NS / 64, CC / 64), 256, 0, stream>>>(wv, xsbuf, bv, vbuf, NS, CC);
  // transpose+split K; split V (fp16 hi/lo for MFMA)
  tsplit_kernel<<<dim3(NS / 64, HEADS), 256, 0, stream>>>(kbuf, kth, ktl, NS);
  vsplit_kernel<<<dim3(CC * NS / 256), 256, 0, stream>>>(vbuf, vhb, vlb);
  // MFMA flash attention (Q read fp32 + split in-kernel)
  attn_kernel<<<dim3(HWN / 64, HEADS), 256, 0, stream>>>(qbuf, kth, ktl,
                                                         vhb, vlb, posws, rpe, obuf);
  // y = wo @ out + bo
  gemm_bias_kernel<<<dim3(HWN / 64, CC / 64), 256, 0, stream>>>(wo, obuf, bo, y_out, HWN, CC);
}